// Round 1
// baseline (2340.727 us; speedup 1.0000x reference)
//
#include <hip/hip_runtime.h>

#define B_ 16
#define N_ 1024
#define F_ 768
#define H_ 128

// ---------------------------------------------------------------------------
// helpers
// ---------------------------------------------------------------------------
__device__ __forceinline__ float blockReduceSum256(float v) {
  __shared__ float red[4];
  #pragma unroll
  for (int o = 32; o > 0; o >>= 1) v += __shfl_down(v, o, 64);
  if ((threadIdx.x & 63) == 0) red[threadIdx.x >> 6] = v;
  __syncthreads();
  float r = red[0] + red[1] + red[2] + red[3];
  __syncthreads();
  return r;
}

// ---------------------------------------------------------------------------
// K1: per row of adj: dis_bin = rsqrt(1+nnz), dc = rsqrt(1+rowsum), dr = mask*dc
// ---------------------------------------------------------------------------
__global__ __launch_bounds__(256) void k_degrees(
    const float* __restrict__ adj, float* __restrict__ dis_bin,
    float* __restrict__ dr, float* __restrict__ dc) {
  long row = blockIdx.x;
  const float* a = adj + row * N_;
  float cnt = 0.f, sw = 0.f;
  for (int j = threadIdx.x; j < N_; j += 256) {
    float v = a[j];
    if (v != 0.0f) { cnt += 1.0f; sw += v; }
  }
  __shared__ float r1[4], r2[4];
  #pragma unroll
  for (int o = 32; o > 0; o >>= 1) { cnt += __shfl_down(cnt, o, 64); sw += __shfl_down(sw, o, 64); }
  if ((threadIdx.x & 63) == 0) { r1[threadIdx.x >> 6] = cnt; r2[threadIdx.x >> 6] = sw; }
  __syncthreads();
  if (threadIdx.x == 0) {
    float c = r1[0] + r1[1] + r1[2] + r1[3];
    float s = r2[0] + r2[1] + r2[2] + r2[3];
    dis_bin[row] = rsqrtf(c + 1.0f);
    float d = rsqrtf(s + 1.0f);
    dc[row] = d;
    dr[row] = (s > 0.0f) ? d : 0.0f;
  }
}

// ---------------------------------------------------------------------------
// Tiled GEMM: C[b] = op(A[b]) @ B[b] with epilogues.
// MODE 0: C=acc
// MODE 1: C=scale[m]*acc
// MODE 2: C=relu(scale[m]*(acc+Add[m,n])+bias[n])
// MODE 3: C=tanh(scale[m]*(acc+Add[m,n])+bias[n])
// MODE 4: C=floor(acc*1e4)/1e4
// TRANSA: A stored [K,M] (ld=M) ; else [M,K] (ld=K).  BINA: a = (a!=0)
// ---------------------------------------------------------------------------
#define TM 64
#define TN 64
#define TK 16

template<int TRANSA, int BINA, int MODE>
__global__ __launch_bounds__(256) void gemm(
    const float* __restrict__ A, const float* __restrict__ Bm,
    float* __restrict__ C, int M, int N, int K,
    long sA, long sB, long sC,
    const float* __restrict__ scale, long sScale,
    const float* __restrict__ Add, long sAdd,
    const float* __restrict__ bias) {
  int bz = blockIdx.z;
  const float* Ab = A + (long)bz * sA;
  const float* Bb = Bm + (long)bz * sB;
  float* Cb = C + (long)bz * sC;
  int m0 = blockIdx.y * TM, n0 = blockIdx.x * TN;
  __shared__ float As[TK][TM + 1];
  __shared__ float Bs[TK][TN + 1];
  float acc[4][4] = {};
  int tid = threadIdx.x;
  int tx = tid & 15, ty = tid >> 4;

  for (int k0 = 0; k0 < K; k0 += TK) {
    if (TRANSA == 0) {
      #pragma unroll
      for (int l = 0; l < 4; ++l) {
        int idx = tid + l * 256;
        int k = idx & 15, m = idx >> 4;
        float a = Ab[(long)(m0 + m) * K + (k0 + k)];
        if (BINA) a = (a != 0.0f) ? 1.0f : 0.0f;
        As[k][m] = a;
      }
    } else {
      #pragma unroll
      for (int l = 0; l < 4; ++l) {
        int idx = tid + l * 256;
        int m = idx & 63, k = idx >> 6;
        float a = Ab[(long)(k0 + k) * M + (m0 + m)];
        if (BINA) a = (a != 0.0f) ? 1.0f : 0.0f;
        As[k][m] = a;
      }
    }
    #pragma unroll
    for (int l = 0; l < 4; ++l) {
      int idx = tid + l * 256;
      int n = idx & 63, k = idx >> 6;
      Bs[k][n] = Bb[(long)(k0 + k) * N + (n0 + n)];
    }
    __syncthreads();
    #pragma unroll
    for (int kk = 0; kk < TK; ++kk) {
      float av[4], bv[4];
      #pragma unroll
      for (int i = 0; i < 4; ++i) av[i] = As[kk][ty * 4 + i];
      #pragma unroll
      for (int j = 0; j < 4; ++j) bv[j] = Bs[kk][tx * 4 + j];
      #pragma unroll
      for (int i = 0; i < 4; ++i)
        #pragma unroll
        for (int j = 0; j < 4; ++j) acc[i][j] += av[i] * bv[j];
    }
    __syncthreads();
  }

  #pragma unroll
  for (int i = 0; i < 4; ++i) {
    int row = m0 + ty * 4 + i;
    float sc = 0.f;
    if constexpr (MODE == 1 || MODE == 2 || MODE == 3)
      sc = scale[(long)bz * sScale + row];
    #pragma unroll
    for (int j = 0; j < 4; ++j) {
      int col = n0 + tx * 4 + j;
      float v = acc[i][j];
      if constexpr (MODE == 1) {
        v = sc * v;
      } else if constexpr (MODE == 2) {
        v = sc * (v + Add[(long)bz * sAdd + (long)row * N + col]) + bias[col];
        v = fmaxf(v, 0.0f);
      } else if constexpr (MODE == 3) {
        v = sc * (v + Add[(long)bz * sAdd + (long)row * N + col]) + bias[col];
        v = tanhf(v);
      } else if constexpr (MODE == 4) {
        v = floorf(v * 10000.0f) / 10000.0f;
      }
      Cb[(long)row * N + col] = v;
    }
  }
}

// ---------------------------------------------------------------------------
// K4: t[row] = dot(x1[row,:], Watt)
// ---------------------------------------------------------------------------
__global__ __launch_bounds__(256) void k_att_dot(
    const float* __restrict__ x1, const float* __restrict__ Watt,
    float* __restrict__ t) {
  long row = blockIdx.x;
  float v = 0.f;
  if (threadIdx.x < H_) v = x1[row * H_ + threadIdx.x] * Watt[threadIdx.x];
  float s = blockReduceSum256(v);
  if (threadIdx.x == 0) t[row] = s;
}

// ---------------------------------------------------------------------------
// K5: alpha[b,i] = sigmoid((dis_i*(sum_j bin_ij dis_j t_j + dis_i t_i)+batt)^2)
// ---------------------------------------------------------------------------
__global__ __launch_bounds__(256) void k_alpha(
    const float* __restrict__ adj, const float* __restrict__ dis_bin,
    const float* __restrict__ t, const float* __restrict__ batt,
    float* __restrict__ alpha) {
  long row = blockIdx.x;
  int b = (int)(row >> 10), i = (int)(row & 1023);
  const float* a = adj + row * N_;
  const float* db = dis_bin + (long)b * N_;
  const float* tb = t + (long)b * N_;
  float s = 0.f;
  for (int j = threadIdx.x; j < N_; j += 256)
    if (a[j] != 0.0f) s += db[j] * tb[j];
  s = blockReduceSum256(s);
  if (threadIdx.x == 0) {
    float di = db[i];
    float pre = di * (s + di * tb[i]) + batt[0];
    float z = pre * pre;
    alpha[row] = 1.0f / (1.0f + expf(-z));
  }
}

// ---------------------------------------------------------------------------
// K6: per-batch stable descending sort of alpha, cut, index_mask, cut_alpha
// ---------------------------------------------------------------------------
__global__ __launch_bounds__(1024) void k_cutmask(
    const float* __restrict__ alpha, const int* __restrict__ num_sent,
    const int* __restrict__ nout, float* __restrict__ index_mask,
    float* __restrict__ ca) {
  int b = blockIdx.x, tid = threadIdx.x;
  __shared__ unsigned long long keys[N_];
  __shared__ int cs[N_];
  __shared__ int pos_s;
  float av = alpha[(long)b * N_ + tid];
  unsigned int bits = __float_as_uint(av);
  keys[tid] = ((unsigned long long)(0xFFFFFFFFu - bits) << 32) | (unsigned int)tid;
  __syncthreads();
  for (int kk = 2; kk <= N_; kk <<= 1) {
    for (int j = kk >> 1; j > 0; j >>= 1) {
      int ixj = tid ^ j;
      if (ixj > tid) {
        unsigned long long x = keys[tid], y = keys[ixj];
        bool up = ((tid & kk) == 0);
        if ((x > y) == up) { keys[tid] = y; keys[ixj] = x; }
      }
      __syncthreads();
    }
  }
  int ns = num_sent[b];
  int idx = (int)(keys[tid] & 0xFFFFFFFFull);
  cs[tid] = (idx < ns) ? 1 : 0;
  __syncthreads();
  for (int off = 1; off < N_; off <<= 1) {
    int add = (tid >= off) ? cs[tid - off] : 0;
    __syncthreads();
    cs[tid] += add;
    __syncthreads();
  }
  int k = nout[0];
  if (tid == 0) pos_s = 0;
  __syncthreads();
  if (cs[tid] >= k && (tid == 0 || cs[tid - 1] < k)) pos_s = tid;
  __syncthreads();
  float cut = __uint_as_float(0xFFFFFFFFu - (unsigned int)(keys[pos_s] >> 32));
  float myalpha = __uint_as_float(0xFFFFFFFFu - (unsigned int)(keys[tid] >> 32));
  index_mask[(long)b * N_ + idx] = (tid <= pos_s) ? 1.0f : 0.0f;
  ca[(long)b * N_ + idx] = fmaxf((myalpha + 1e-7f) - cut, 0.0f);
}

// ---------------------------------------------------------------------------
// K7: S[b,i,j] = dr_i*(adj_ij+delta_ij)*dc_j*ca_j, then L1 row-normalize
// ---------------------------------------------------------------------------
__global__ __launch_bounds__(256) void k_build_S(
    const float* __restrict__ adj, const float* __restrict__ dr,
    const float* __restrict__ dc, const float* __restrict__ ca,
    float* __restrict__ S) {
  long row = blockIdx.x;
  int b = (int)(row >> 10), i = (int)(row & 1023);
  const float* a = adj + row * N_;
  const float* dcb = dc + (long)b * N_;
  const float* cab = ca + (long)b * N_;
  float dri = dr[row];
  __shared__ float pre[N_];
  float ls = 0.f;
  for (int j = threadIdx.x; j < N_; j += 256) {
    float avv = a[j] + ((j == i) ? 1.0f : 0.0f);
    float v = dri * avv * dcb[j] * cab[j];
    pre[j] = v;
    ls += v;
  }
  float sum = blockReduceSum256(ls);
  float denom = fmaxf(sum, 1e-12f);
  for (int j = threadIdx.x; j < N_; j += 256)
    S[row * N_ + j] = pre[j] / denom;
}

// ---------------------------------------------------------------------------
// K11: dis2 = rsqrt(1 + nnz(coarse_adj row))
// ---------------------------------------------------------------------------
__global__ __launch_bounds__(256) void k_deg2(
    const float* __restrict__ cadj, float* __restrict__ dis2) {
  long row = blockIdx.x;
  const float* a = cadj + row * N_;
  float cnt = 0.f;
  for (int j = threadIdx.x; j < N_; j += 256)
    if (a[j] != 0.0f) cnt += 1.0f;
  float s = blockReduceSum256(cnt);
  if (threadIdx.x == 0) dis2[row] = rsqrtf(s + 1.0f);
}

// ---------------------------------------------------------------------------
// row mean over width W
// ---------------------------------------------------------------------------
template<int W>
__global__ __launch_bounds__(256) void k_rowmean(
    const float* __restrict__ X, float* __restrict__ out) {
  long row = blockIdx.x;
  float s = 0.f;
  for (int j = threadIdx.x; j < W; j += 256) s += X[row * W + j];
  float r = blockReduceSum256(s);
  if (threadIdx.x == 0) out[row] = r / (float)W;
}

// ---------------------------------------------------------------------------
extern "C" void kernel_launch(void* const* d_in, const int* in_sizes, int n_in,
                              void* d_out, int out_size, void* d_ws, size_t ws_size,
                              hipStream_t stream) {
  const float* x       = (const float*)d_in[0];
  const float* adj     = (const float*)d_in[1];
  const int*   nsent   = (const int*)d_in[2];
  const float* W1      = (const float*)d_in[3];
  const float* b1      = (const float*)d_in[4];
  const float* Watt    = (const float*)d_in[5];
  const float* batt    = (const float*)d_in[6];
  const float* W2      = (const float*)d_in[7];
  const float* b2      = (const float*)d_in[8];
  const int*   nout    = (const int*)d_in[9];

  const long NN = (long)N_ * N_;
  const long NH = (long)N_ * H_;
  const long NF = (long)N_ * F_;
  const int BN = B_ * N_;

  // output layout (flat concat, f32)
  float* out_x2   = (float*)d_out;
  float* out_cx   = out_x2 + (long)B_ * NF;
  float* out_cadj = out_cx + (long)B_ * NH;
  float* out_S    = out_cadj + (long)B_ * NN;
  float* out_im   = out_S + (long)B_ * NN;
  float* out_xs0  = out_im + BN;
  float* out_xs1  = out_xs0 + BN;

  // workspace layout
  float* ws = (float*)d_ws;
  float* P1      = ws;                 // B*N*H
  float* x1      = P1 + (long)B_ * NH; // B*N*H
  float* t       = x1 + (long)B_ * NH; // B*N
  float* alpha   = t + BN;
  float* dis_bin = alpha + BN;
  float* dr      = dis_bin + BN;
  float* dc      = dr + BN;
  float* ca      = dc + BN;
  float* dis2    = ca + BN;
  float* StA     = dis2 + BN;          // B*N*N
  float* P2      = StA;                // alias: StA dead after G7

  // K1: degrees
  k_degrees<<<dim3(BN), dim3(256), 0, stream>>>(adj, dis_bin, dr, dc);

  // G1: P1 = dis_bin .* (x @ W1)   [16384x768]x[768x128]
  gemm<0, 0, 1><<<dim3(H_ / TN, BN / TM, 1), dim3(256), 0, stream>>>(
      x, W1, P1, BN, H_, F_, 0, 0, 0, dis_bin, 0, nullptr, 0, nullptr);

  // G2: x1 = relu(dis_i*(Bin(adj)@P1 + P1_i) + b1)   per batch
  gemm<0, 1, 2><<<dim3(H_ / TN, N_ / TM, B_), dim3(256), 0, stream>>>(
      adj, P1, x1, N_, H_, N_, NN, NH, NH, dis_bin, N_, P1, NH, b1);

  // K4: t = x1 @ Watt
  k_att_dot<<<dim3(BN), dim3(256), 0, stream>>>(x1, Watt, t);

  // K5: alpha
  k_alpha<<<dim3(BN), dim3(256), 0, stream>>>(adj, dis_bin, t, batt, alpha);

  // K6: sort / cut / index_mask / cut_alpha
  k_cutmask<<<dim3(B_), dim3(1024), 0, stream>>>(alpha, nsent, nout, out_im, ca);

  // K7: S
  k_build_S<<<dim3(BN), dim3(256), 0, stream>>>(adj, dr, dc, ca, out_S);

  // G5: coarse_x = S^T @ x1
  gemm<1, 0, 0><<<dim3(H_ / TN, N_ / TM, B_), dim3(256), 0, stream>>>(
      out_S, x1, out_cx, N_, H_, N_, NN, NH, NH, nullptr, 0, nullptr, 0, nullptr);

  // xs0
  k_rowmean<H_><<<dim3(BN), dim3(256), 0, stream>>>(out_cx, out_xs0);

  // G6: StA = S^T @ adj
  gemm<1, 0, 0><<<dim3(N_ / TN, N_ / TM, B_), dim3(256), 0, stream>>>(
      out_S, adj, StA, N_, N_, N_, NN, NN, NN, nullptr, 0, nullptr, 0, nullptr);

  // G7: coarse_adj = floorq(StA @ S)
  gemm<0, 0, 4><<<dim3(N_ / TN, N_ / TM, B_), dim3(256), 0, stream>>>(
      StA, out_S, out_cadj, N_, N_, N_, NN, NN, NN, nullptr, 0, nullptr, 0, nullptr);

  // K11: dis2
  k_deg2<<<dim3(BN), dim3(256), 0, stream>>>(out_cadj, dis2);

  // G8: P2 = dis2 .* (coarse_x @ W2)  [16384x128]x[128x768]
  gemm<0, 0, 1><<<dim3(F_ / TN, BN / TM, 1), dim3(256), 0, stream>>>(
      out_cx, W2, P2, BN, F_, H_, 0, 0, 0, dis2, 0, nullptr, 0, nullptr);

  // G9: x2 = tanh(dis2_i*(Bin(coarse_adj)@P2 + P2_i) + b2)
  gemm<0, 1, 3><<<dim3(F_ / TN, N_ / TM, B_), dim3(256), 0, stream>>>(
      out_cadj, P2, out_x2, N_, F_, N_, NN, NF, NF, dis2, N_, P2, NF, b2);

  // xs1
  k_rowmean<F_><<<dim3(BN), dim3(256), 0, stream>>>(out_x2, out_xs1);
}

// Round 2
// 723.473 us; speedup vs baseline: 3.2354x; 3.2354x over previous
//
#include <hip/hip_runtime.h>

#define B_ 16
#define N_ 1024
#define F_ 768
#define H_ 128

typedef float f32x4 __attribute__((ext_vector_type(4)));
typedef short s16x8 __attribute__((ext_vector_type(8)));
typedef unsigned short u16;
typedef u16 u16x8 __attribute__((ext_vector_type(8)));

__device__ __forceinline__ u16 f2b(float f) {
  unsigned u = __float_as_uint(f);
  unsigned r = (u + 0x7FFFu + ((u >> 16) & 1u)) >> 16;
  return (u16)r;
}

// ---------------------------------------------------------------------------
// helpers
// ---------------------------------------------------------------------------
__device__ __forceinline__ float blockReduceSum256(float v) {
  __shared__ float red[4];
  #pragma unroll
  for (int o = 32; o > 0; o >>= 1) v += __shfl_down(v, o, 64);
  if ((threadIdx.x & 63) == 0) red[threadIdx.x >> 6] = v;
  __syncthreads();
  float r = red[0] + red[1] + red[2] + red[3];
  __syncthreads();
  return r;
}

// ---------------------------------------------------------------------------
// K1: per row of adj: dis_bin = rsqrt(1+nnz), dc = rsqrt(1+rowsum), dr = mask*dc
// ---------------------------------------------------------------------------
__global__ __launch_bounds__(256) void k_degrees(
    const float* __restrict__ adj, float* __restrict__ dis_bin,
    float* __restrict__ dr, float* __restrict__ dc) {
  long row = blockIdx.x;
  const float* a = adj + row * N_;
  float cnt = 0.f, sw = 0.f;
  for (int j = threadIdx.x; j < N_; j += 256) {
    float v = a[j];
    if (v != 0.0f) { cnt += 1.0f; sw += v; }
  }
  __shared__ float r1[4], r2[4];
  #pragma unroll
  for (int o = 32; o > 0; o >>= 1) { cnt += __shfl_down(cnt, o, 64); sw += __shfl_down(sw, o, 64); }
  if ((threadIdx.x & 63) == 0) { r1[threadIdx.x >> 6] = cnt; r2[threadIdx.x >> 6] = sw; }
  __syncthreads();
  if (threadIdx.x == 0) {
    float c = r1[0] + r1[1] + r1[2] + r1[3];
    float s = r2[0] + r2[1] + r2[2] + r2[3];
    dis_bin[row] = rsqrtf(c + 1.0f);
    float d = rsqrtf(s + 1.0f);
    dc[row] = d;
    dr[row] = (s > 0.0f) ? d : 0.0f;
  }
}

// ---------------------------------------------------------------------------
// f32 tiled GEMM (small ops only). Epilogues as before.
// ---------------------------------------------------------------------------
#define TM 64
#define TN 64
#define TK 16

template<int TRANSA, int BINA, int MODE>
__global__ __launch_bounds__(256) void gemm(
    const float* __restrict__ A, const float* __restrict__ Bm,
    float* __restrict__ C, int M, int N, int K,
    long sA, long sB, long sC,
    const float* __restrict__ scale, long sScale,
    const float* __restrict__ Add, long sAdd,
    const float* __restrict__ bias) {
  int bz = blockIdx.z;
  const float* Ab = A + (long)bz * sA;
  const float* Bb = Bm + (long)bz * sB;
  float* Cb = C + (long)bz * sC;
  int m0 = blockIdx.y * TM, n0 = blockIdx.x * TN;
  __shared__ float As[TK][TM + 1];
  __shared__ float Bs[TK][TN + 1];
  float acc[4][4] = {};
  int tid = threadIdx.x;
  int tx = tid & 15, ty = tid >> 4;

  for (int k0 = 0; k0 < K; k0 += TK) {
    if (TRANSA == 0) {
      #pragma unroll
      for (int l = 0; l < 4; ++l) {
        int idx = tid + l * 256;
        int k = idx & 15, m = idx >> 4;
        float a = Ab[(long)(m0 + m) * K + (k0 + k)];
        if (BINA) a = (a != 0.0f) ? 1.0f : 0.0f;
        As[k][m] = a;
      }
    } else {
      #pragma unroll
      for (int l = 0; l < 4; ++l) {
        int idx = tid + l * 256;
        int m = idx & 63, k = idx >> 6;
        float a = Ab[(long)(k0 + k) * M + (m0 + m)];
        if (BINA) a = (a != 0.0f) ? 1.0f : 0.0f;
        As[k][m] = a;
      }
    }
    #pragma unroll
    for (int l = 0; l < 4; ++l) {
      int idx = tid + l * 256;
      int n = idx & 63, k = idx >> 6;
      Bs[k][n] = Bb[(long)(k0 + k) * N + (n0 + n)];
    }
    __syncthreads();
    #pragma unroll
    for (int kk = 0; kk < TK; ++kk) {
      float av[4], bv[4];
      #pragma unroll
      for (int i = 0; i < 4; ++i) av[i] = As[kk][ty * 4 + i];
      #pragma unroll
      for (int j = 0; j < 4; ++j) bv[j] = Bs[kk][tx * 4 + j];
      #pragma unroll
      for (int i = 0; i < 4; ++i)
        #pragma unroll
        for (int j = 0; j < 4; ++j) acc[i][j] += av[i] * bv[j];
    }
    __syncthreads();
  }

  #pragma unroll
  for (int i = 0; i < 4; ++i) {
    int row = m0 + ty * 4 + i;
    float sc = 0.f;
    if constexpr (MODE == 1 || MODE == 2 || MODE == 3)
      sc = scale[(long)bz * sScale + row];
    #pragma unroll
    for (int j = 0; j < 4; ++j) {
      int col = n0 + tx * 4 + j;
      float v = acc[i][j];
      if constexpr (MODE == 1) {
        v = sc * v;
      } else if constexpr (MODE == 2) {
        v = sc * (v + Add[(long)bz * sAdd + (long)row * N + col]) + bias[col];
        v = fmaxf(v, 0.0f);
      } else if constexpr (MODE == 3) {
        v = sc * (v + Add[(long)bz * sAdd + (long)row * N + col]) + bias[col];
        v = tanhf(v);
      } else if constexpr (MODE == 4) {
        v = floorf(v * 10000.0f) / 10000.0f;
      }
      Cb[(long)row * N + col] = v;
    }
  }
}

// ---------------------------------------------------------------------------
// bf16 MFMA GEMM: C[b][M][N] = A[b][M][K] @ B[b][K][N], B given TRANSPOSED
// as Bt[b][N][K]. 128x128 tile, 4 waves, 16x16x32 MFMA, padded LDS (40 elems).
// MODE 0: f32 C = acc
// MODE 1: bf16 C = acc
// MODE 2: f32 C = floor(acc*1e4)/1e4
// MODE 3: f32 C = tanh(scale[row]*(acc+Add[row][col])+bias[col])
// ---------------------------------------------------------------------------
template<int MODE>
__global__ __launch_bounds__(256) void mgemm(
    const u16* __restrict__ A, const u16* __restrict__ Bt, void* __restrict__ Cv,
    int M, int N, int K, long sA, long sB, long sC,
    const float* __restrict__ scale, const float* __restrict__ Add, long sAdd,
    const float* __restrict__ bias) {
  int bz = blockIdx.z;
  int m0 = blockIdx.y * 128, n0 = blockIdx.x * 128;
  const u16* Ab = A + (long)bz * sA + (long)m0 * K;
  const u16* Bb = Bt + (long)bz * sB + (long)n0 * K;
  __shared__ u16 As[128 * 40];  // rows padded to 40 elems (80B) -> conflict-free b128
  __shared__ u16 Bs[128 * 40];
  int tid = threadIdx.x;
  int lane = tid & 63, wave = tid >> 6;
  int wr = wave >> 1, wc = wave & 1;
  int kg = lane >> 4, r16 = lane & 15;
  f32x4 acc[4][4] = {};

  for (int k0 = 0; k0 < K; k0 += 32) {
    #pragma unroll
    for (int i = 0; i < 2; ++i) {
      int u = tid + i * 256;
      int row = u >> 2, seg = u & 3;
      long goff = (long)row * K + k0 + seg * 8;
      *(u16x8*)(&As[row * 40 + seg * 8]) = *(const u16x8*)(Ab + goff);
      *(u16x8*)(&Bs[row * 40 + seg * 8]) = *(const u16x8*)(Bb + goff);
    }
    __syncthreads();
    s16x8 af[4], bfr[4];
    #pragma unroll
    for (int m = 0; m < 4; ++m)
      af[m] = *(const s16x8*)(&As[(wr * 64 + m * 16 + r16) * 40 + kg * 8]);
    #pragma unroll
    for (int n = 0; n < 4; ++n)
      bfr[n] = *(const s16x8*)(&Bs[(wc * 64 + n * 16 + r16) * 40 + kg * 8]);
    #pragma unroll
    for (int m = 0; m < 4; ++m)
      #pragma unroll
      for (int n = 0; n < 4; ++n)
        acc[m][n] = __builtin_amdgcn_mfma_f32_16x16x32_bf16(af[m], bfr[n], acc[m][n], 0, 0, 0);
    __syncthreads();
  }

  #pragma unroll
  for (int m = 0; m < 4; ++m) {
    #pragma unroll
    for (int r = 0; r < 4; ++r) {
      int row = m0 + wr * 64 + m * 16 + kg * 4 + r;
      float sc = 0.f;
      if constexpr (MODE == 3) sc = scale[(long)bz * N_ + row];
      #pragma unroll
      for (int n = 0; n < 4; ++n) {
        int col = n0 + wc * 64 + n * 16 + r16;
        float v = acc[m][n][r];
        long cidx = (long)bz * sC + (long)row * N + col;
        if constexpr (MODE == 0) {
          ((float*)Cv)[cidx] = v;
        } else if constexpr (MODE == 1) {
          ((u16*)Cv)[cidx] = f2b(v);
        } else if constexpr (MODE == 2) {
          ((float*)Cv)[cidx] = floorf(v * 10000.0f) / 10000.0f;
        } else {
          v = sc * (v + Add[(long)bz * sAdd + (long)row * N + col]) + bias[col];
          ((float*)Cv)[cidx] = tanhf(v);
        }
      }
    }
  }
}

// ---------------------------------------------------------------------------
// transpose-convert: X[b][R][C] f32 -> Y[b][C][R] bf16
// ---------------------------------------------------------------------------
__global__ __launch_bounds__(256) void k_convT(
    const float* __restrict__ X, u16* __restrict__ Y, int R, int C,
    long sX, long sY) {
  __shared__ float tile[32][33];
  const float* Xb = X + (long)blockIdx.z * sX;
  u16* Yb = Y + (long)blockIdx.z * sY;
  int tx = threadIdx.x & 31, ty = threadIdx.x >> 5;
  int r0 = blockIdx.y * 32, c0 = blockIdx.x * 32;
  #pragma unroll
  for (int i = 0; i < 4; ++i)
    tile[ty + i * 8][tx] = Xb[(long)(r0 + ty + i * 8) * C + (c0 + tx)];
  __syncthreads();
  #pragma unroll
  for (int i = 0; i < 4; ++i)
    Yb[(long)(c0 + ty + i * 8) * R + (r0 + tx)] = f2b(tile[tx][ty + i * 8]);
}

// ---------------------------------------------------------------------------
// binarize-convert: Y[i] = X[i] != 0 ? 1.0bf16 : 0
// ---------------------------------------------------------------------------
__global__ __launch_bounds__(256) void k_convbin(
    const float* __restrict__ X, u16* __restrict__ Y, long n) {
  long i = (long)blockIdx.x * 256 + threadIdx.x;
  long stride = (long)gridDim.x * 256;
  for (; i < n; i += stride)
    Y[i] = (X[i] != 0.0f) ? (u16)0x3F80 : (u16)0;
}

// ---------------------------------------------------------------------------
// K4: t[row] = dot(x1[row,:], Watt)
// ---------------------------------------------------------------------------
__global__ __launch_bounds__(256) void k_att_dot(
    const float* __restrict__ x1, const float* __restrict__ Watt,
    float* __restrict__ t) {
  long row = blockIdx.x;
  float v = 0.f;
  if (threadIdx.x < H_) v = x1[row * H_ + threadIdx.x] * Watt[threadIdx.x];
  float s = blockReduceSum256(v);
  if (threadIdx.x == 0) t[row] = s;
}

// ---------------------------------------------------------------------------
// K5: alpha[b,i] = sigmoid((dis_i*(sum_j bin_ij dis_j t_j + dis_i t_i)+batt)^2)
// ---------------------------------------------------------------------------
__global__ __launch_bounds__(256) void k_alpha(
    const float* __restrict__ adj, const float* __restrict__ dis_bin,
    const float* __restrict__ t, const float* __restrict__ batt,
    float* __restrict__ alpha) {
  long row = blockIdx.x;
  int b = (int)(row >> 10), i = (int)(row & 1023);
  const float* a = adj + row * N_;
  const float* db = dis_bin + (long)b * N_;
  const float* tb = t + (long)b * N_;
  float s = 0.f;
  for (int j = threadIdx.x; j < N_; j += 256)
    if (a[j] != 0.0f) s += db[j] * tb[j];
  s = blockReduceSum256(s);
  if (threadIdx.x == 0) {
    float di = db[i];
    float pre = di * (s + di * tb[i]) + batt[0];
    float z = pre * pre;
    alpha[row] = 1.0f / (1.0f + expf(-z));
  }
}

// ---------------------------------------------------------------------------
// K6: per-batch stable descending sort of alpha, cut, index_mask, cut_alpha
// ---------------------------------------------------------------------------
__global__ __launch_bounds__(1024) void k_cutmask(
    const float* __restrict__ alpha, const int* __restrict__ num_sent,
    const int* __restrict__ nout, float* __restrict__ index_mask,
    float* __restrict__ ca) {
  int b = blockIdx.x, tid = threadIdx.x;
  __shared__ unsigned long long keys[N_];
  __shared__ int cs[N_];
  __shared__ int pos_s;
  float av = alpha[(long)b * N_ + tid];
  unsigned int bits = __float_as_uint(av);
  keys[tid] = ((unsigned long long)(0xFFFFFFFFu - bits) << 32) | (unsigned int)tid;
  __syncthreads();
  for (int kk = 2; kk <= N_; kk <<= 1) {
    for (int j = kk >> 1; j > 0; j >>= 1) {
      int ixj = tid ^ j;
      if (ixj > tid) {
        unsigned long long x = keys[tid], y = keys[ixj];
        bool up = ((tid & kk) == 0);
        if ((x > y) == up) { keys[tid] = y; keys[ixj] = x; }
      }
      __syncthreads();
    }
  }
  int ns = num_sent[b];
  int idx = (int)(keys[tid] & 0xFFFFFFFFull);
  cs[tid] = (idx < ns) ? 1 : 0;
  __syncthreads();
  for (int off = 1; off < N_; off <<= 1) {
    int add = (tid >= off) ? cs[tid - off] : 0;
    __syncthreads();
    cs[tid] += add;
    __syncthreads();
  }
  int k = nout[0];
  if (tid == 0) pos_s = 0;
  __syncthreads();
  if (cs[tid] >= k && (tid == 0 || cs[tid - 1] < k)) pos_s = tid;
  __syncthreads();
  float cut = __uint_as_float(0xFFFFFFFFu - (unsigned int)(keys[pos_s] >> 32));
  float myalpha = __uint_as_float(0xFFFFFFFFu - (unsigned int)(keys[tid] >> 32));
  index_mask[(long)b * N_ + idx] = (tid <= pos_s) ? 1.0f : 0.0f;
  ca[(long)b * N_ + idx] = fmaxf((myalpha + 1e-7f) - cut, 0.0f);
}

// ---------------------------------------------------------------------------
// K7: S[b,i,j] = dr_i*(adj_ij+delta_ij)*dc_j*ca_j, then L1 row-normalize
// ---------------------------------------------------------------------------
__global__ __launch_bounds__(256) void k_build_S(
    const float* __restrict__ adj, const float* __restrict__ dr,
    const float* __restrict__ dc, const float* __restrict__ ca,
    float* __restrict__ S) {
  long row = blockIdx.x;
  int b = (int)(row >> 10), i = (int)(row & 1023);
  const float* a = adj + row * N_;
  const float* dcb = dc + (long)b * N_;
  const float* cab = ca + (long)b * N_;
  float dri = dr[row];
  __shared__ float pre[N_];
  float ls = 0.f;
  for (int j = threadIdx.x; j < N_; j += 256) {
    float avv = a[j] + ((j == i) ? 1.0f : 0.0f);
    float v = dri * avv * dcb[j] * cab[j];
    pre[j] = v;
    ls += v;
  }
  float sum = blockReduceSum256(ls);
  float denom = fmaxf(sum, 1e-12f);
  for (int j = threadIdx.x; j < N_; j += 256)
    S[row * N_ + j] = pre[j] / denom;
}

// ---------------------------------------------------------------------------
// K11: dis2 = rsqrt(1 + nnz(coarse_adj row))
// ---------------------------------------------------------------------------
__global__ __launch_bounds__(256) void k_deg2(
    const float* __restrict__ cadj, float* __restrict__ dis2) {
  long row = blockIdx.x;
  const float* a = cadj + row * N_;
  float cnt = 0.f;
  for (int j = threadIdx.x; j < N_; j += 256)
    if (a[j] != 0.0f) cnt += 1.0f;
  float s = blockReduceSum256(cnt);
  if (threadIdx.x == 0) dis2[row] = rsqrtf(s + 1.0f);
}

// ---------------------------------------------------------------------------
// row mean over width W
// ---------------------------------------------------------------------------
template<int W>
__global__ __launch_bounds__(256) void k_rowmean(
    const float* __restrict__ X, float* __restrict__ out) {
  long row = blockIdx.x;
  float s = 0.f;
  for (int j = threadIdx.x; j < W; j += 256) s += X[row * W + j];
  float r = blockReduceSum256(s);
  if (threadIdx.x == 0) out[row] = r / (float)W;
}

// ---------------------------------------------------------------------------
extern "C" void kernel_launch(void* const* d_in, const int* in_sizes, int n_in,
                              void* d_out, int out_size, void* d_ws, size_t ws_size,
                              hipStream_t stream) {
  const float* x       = (const float*)d_in[0];
  const float* adj     = (const float*)d_in[1];
  const int*   nsent   = (const int*)d_in[2];
  const float* W1      = (const float*)d_in[3];
  const float* b1      = (const float*)d_in[4];
  const float* Watt    = (const float*)d_in[5];
  const float* batt    = (const float*)d_in[6];
  const float* W2      = (const float*)d_in[7];
  const float* b2      = (const float*)d_in[8];
  const int*   nout    = (const int*)d_in[9];

  const long NN = (long)N_ * N_;
  const long NH = (long)N_ * H_;
  const long NF = (long)N_ * F_;
  const int BN = B_ * N_;

  // output layout (flat concat, f32)
  float* out_x2   = (float*)d_out;
  float* out_cx   = out_x2 + (long)B_ * NF;
  float* out_cadj = out_cx + (long)B_ * NH;
  float* out_S    = out_cadj + (long)B_ * NN;
  float* out_im   = out_S + (long)B_ * NN;
  float* out_xs0  = out_im + BN;
  float* out_xs1  = out_xs0 + BN;

  // workspace layout (bytes):
  //  P1 f32 8MB | x1 f32 8MB | smalls | St u16 32MB | adjT u16 32MB |
  //  StA u16 32MB | x1T u16 4MB | P2T u16 24MB
  // aliases: P2f f32 (48MB) over adjT+StA (dead after G7); cbin u16 over St
  char* wsb = (char*)d_ws;
  float* P1      = (float*)wsb;
  float* x1      = P1 + (long)B_ * NH;
  float* t       = x1 + (long)B_ * NH;
  float* alpha   = t + BN;
  float* dis_bin = alpha + BN;
  float* dr      = dis_bin + BN;
  float* dc      = dr + BN;
  float* ca      = dc + BN;
  float* dis2    = ca + BN;
  char*  p       = (char*)(dis2 + BN);
  p = (char*)(((size_t)p + 255) & ~(size_t)255);
  u16* St    = (u16*)p;                 p += (long)B_ * NN * 2;
  u16* adjT  = (u16*)p;                 p += (long)B_ * NN * 2;
  u16* StA   = (u16*)p;                 p += (long)B_ * NN * 2;
  u16* x1T   = (u16*)p;                 p += (long)B_ * NH * 2;
  u16* P2T   = (u16*)p;                 p += (long)B_ * NF * 2;
  float* P2f = (float*)adjT;            // 48MB over adjT(32)+StA(16)
  u16*   cbin = St;                     // 32MB over St

  // K1: degrees
  k_degrees<<<dim3(BN), dim3(256), 0, stream>>>(adj, dis_bin, dr, dc);

  // G1: P1 = dis_bin .* (x @ W1)  (f32)
  gemm<0, 0, 1><<<dim3(H_ / TN, BN / TM, 1), dim3(256), 0, stream>>>(
      x, W1, P1, BN, H_, F_, 0, 0, 0, dis_bin, 0, nullptr, 0, nullptr);

  // G2: x1 = relu(dis_i*(Bin(adj)@P1 + P1_i) + b1)  (f32)
  gemm<0, 1, 2><<<dim3(H_ / TN, N_ / TM, B_), dim3(256), 0, stream>>>(
      adj, P1, x1, N_, H_, N_, NN, NH, NH, dis_bin, N_, P1, NH, b1);

  // K4/K5/K6/K7 (all f32, unchanged)
  k_att_dot<<<dim3(BN), dim3(256), 0, stream>>>(x1, Watt, t);
  k_alpha<<<dim3(BN), dim3(256), 0, stream>>>(adj, dis_bin, t, batt, alpha);
  k_cutmask<<<dim3(B_), dim3(1024), 0, stream>>>(alpha, nsent, nout, out_im, ca);
  k_build_S<<<dim3(BN), dim3(256), 0, stream>>>(adj, dr, dc, ca, out_S);

  // conversions: St = S^T, adjT = adj^T, x1T = x1^T (bf16)
  k_convT<<<dim3(N_ / 32, N_ / 32, B_), dim3(256), 0, stream>>>(
      out_S, St, N_, N_, NN, NN);
  k_convT<<<dim3(N_ / 32, N_ / 32, B_), dim3(256), 0, stream>>>(
      adj, adjT, N_, N_, NN, NN);
  k_convT<<<dim3(H_ / 32, N_ / 32, B_), dim3(256), 0, stream>>>(
      x1, x1T, N_, H_, NH, NH);

  // G5: coarse_x = S^T @ x1  (MFMA; A=St [M][K], Bt=x1T [H][K])
  mgemm<0><<<dim3(H_ / 128, N_ / 128, B_), dim3(256), 0, stream>>>(
      St, x1T, out_cx, N_, H_, N_, NN, NH, NH, nullptr, nullptr, 0, nullptr);
  k_rowmean<H_><<<dim3(BN), dim3(256), 0, stream>>>(out_cx, out_xs0);

  // G6: StA = S^T @ adj  (MFMA, bf16 out; A=St, Bt=adjT)
  mgemm<1><<<dim3(N_ / 128, N_ / 128, B_), dim3(256), 0, stream>>>(
      St, adjT, StA, N_, N_, N_, NN, NN, NN, nullptr, nullptr, 0, nullptr);

  // G7: coarse_adj = floorq(StA @ S)  (MFMA; A=StA, Bt=S^T=St)
  mgemm<2><<<dim3(N_ / 128, N_ / 128, B_), dim3(256), 0, stream>>>(
      StA, St, out_cadj, N_, N_, N_, NN, NN, NN, nullptr, nullptr, 0, nullptr);

  // K11: dis2
  k_deg2<<<dim3(BN), dim3(256), 0, stream>>>(out_cadj, dis2);

  // G8: P2f = dis2 .* (coarse_x @ W2)  (f32)
  gemm<0, 0, 1><<<dim3(F_ / TN, BN / TM, 1), dim3(256), 0, stream>>>(
      out_cx, W2, P2f, BN, F_, H_, 0, 0, 0, dis2, 0, nullptr, 0, nullptr);

  // P2T = P2f^T (bf16), cbin = Bin(coarse_adj) (bf16)
  k_convT<<<dim3(F_ / 32, N_ / 32, B_), dim3(256), 0, stream>>>(
      P2f, P2T, N_, F_, NF, NF);
  k_convbin<<<dim3(2048), dim3(256), 0, stream>>>(out_cadj, cbin, (long)B_ * NN);

  // G9: x2 = tanh(dis2_i*(cbin@P2 + P2_i) + b2)  (MFMA; A=cbin, Bt=P2T, Add=P2f)
  mgemm<3><<<dim3(F_ / 128, N_ / 128, B_), dim3(256), 0, stream>>>(
      cbin, P2T, out_x2, N_, F_, N_, NN, NF, NF, dis2, P2f, NF, b2);

  k_rowmean<F_><<<dim3(BN), dim3(256), 0, stream>>>(out_x2, out_xs1);
}

// Round 4
// 607.313 us; speedup vs baseline: 3.8542x; 1.1913x over previous
//
#include <hip/hip_runtime.h>

#define B_ 16
#define N_ 1024
#define F_ 768
#define H_ 128

typedef float f32x4 __attribute__((ext_vector_type(4)));
typedef short s16x8 __attribute__((ext_vector_type(8)));
typedef unsigned short u16;
typedef u16 u16x8 __attribute__((ext_vector_type(8)));
typedef u16 u16x4 __attribute__((ext_vector_type(4)));

__device__ __forceinline__ u16 f2b(float f) {
  unsigned u = __float_as_uint(f);
  unsigned r = (u + 0x7FFFu + ((u >> 16) & 1u)) >> 16;
  return (u16)r;
}

__device__ __forceinline__ void gload16(const u16* g, u16* l) {
  __builtin_amdgcn_global_load_lds(
      (const __attribute__((address_space(1))) unsigned int*)g,
      (__attribute__((address_space(3))) unsigned int*)l, 16, 0, 0);
}

// ---------------------------------------------------------------------------
__device__ __forceinline__ float blockReduceSum256(float v) {
  __shared__ float red[4];
  #pragma unroll
  for (int o = 32; o > 0; o >>= 1) v += __shfl_down(v, o, 64);
  if ((threadIdx.x & 63) == 0) red[threadIdx.x >> 6] = v;
  __syncthreads();
  float r = red[0] + red[1] + red[2] + red[3];
  __syncthreads();
  return r;
}

// ---------------------------------------------------------------------------
// K1: dis_bin = rsqrt(1+nnz), dc = rsqrt(1+rowsum), dr = mask*dc
// ---------------------------------------------------------------------------
__global__ __launch_bounds__(256) void k_degrees(
    const float* __restrict__ adj, float* __restrict__ dis_bin,
    float* __restrict__ dr, float* __restrict__ dc) {
  long row = blockIdx.x;
  const float* a = adj + row * N_;
  float cnt = 0.f, sw = 0.f;
  for (int j = threadIdx.x; j < N_; j += 256) {
    float v = a[j];
    if (v != 0.0f) { cnt += 1.0f; sw += v; }
  }
  __shared__ float r1[4], r2[4];
  #pragma unroll
  for (int o = 32; o > 0; o >>= 1) { cnt += __shfl_down(cnt, o, 64); sw += __shfl_down(sw, o, 64); }
  if ((threadIdx.x & 63) == 0) { r1[threadIdx.x >> 6] = cnt; r2[threadIdx.x >> 6] = sw; }
  __syncthreads();
  if (threadIdx.x == 0) {
    float c = r1[0] + r1[1] + r1[2] + r1[3];
    float s = r2[0] + r2[1] + r2[2] + r2[3];
    dis_bin[row] = rsqrtf(c + 1.0f);
    float d = rsqrtf(s + 1.0f);
    dc[row] = d;
    dr[row] = (s > 0.0f) ? d : 0.0f;
  }
}

// ---------------------------------------------------------------------------
// f32 tiled GEMM (alpha-critical G1 only). MODE 1: C = scale[m]*acc
// ---------------------------------------------------------------------------
#define TM 64
#define TN 64
#define TK 16

template<int TRANSA, int BINA, int MODE>
__global__ __launch_bounds__(256) void gemm(
    const float* __restrict__ A, const float* __restrict__ Bm,
    float* __restrict__ C, int M, int N, int K,
    long sA, long sB, long sC,
    const float* __restrict__ scale, long sScale,
    const float* __restrict__ Add, long sAdd,
    const float* __restrict__ bias) {
  int bz = blockIdx.z;
  const float* Ab = A + (long)bz * sA;
  const float* Bb = Bm + (long)bz * sB;
  float* Cb = C + (long)bz * sC;
  int m0 = blockIdx.y * TM, n0 = blockIdx.x * TN;
  __shared__ float As[TK][TM + 1];
  __shared__ float Bs[TK][TN + 1];
  float acc[4][4] = {};
  int tid = threadIdx.x;
  int tx = tid & 15, ty = tid >> 4;

  for (int k0 = 0; k0 < K; k0 += TK) {
    if (TRANSA == 0) {
      #pragma unroll
      for (int l = 0; l < 4; ++l) {
        int idx = tid + l * 256;
        int k = idx & 15, m = idx >> 4;
        float a = Ab[(long)(m0 + m) * K + (k0 + k)];
        if (BINA) a = (a != 0.0f) ? 1.0f : 0.0f;
        As[k][m] = a;
      }
    } else {
      #pragma unroll
      for (int l = 0; l < 4; ++l) {
        int idx = tid + l * 256;
        int m = idx & 63, k = idx >> 6;
        float a = Ab[(long)(k0 + k) * M + (m0 + m)];
        if (BINA) a = (a != 0.0f) ? 1.0f : 0.0f;
        As[k][m] = a;
      }
    }
    #pragma unroll
    for (int l = 0; l < 4; ++l) {
      int idx = tid + l * 256;
      int n = idx & 63, k = idx >> 6;
      Bs[k][n] = Bb[(long)(k0 + k) * N + (n0 + n)];
    }
    __syncthreads();
    #pragma unroll
    for (int kk = 0; kk < TK; ++kk) {
      float av[4], bv[4];
      #pragma unroll
      for (int i = 0; i < 4; ++i) av[i] = As[kk][ty * 4 + i];
      #pragma unroll
      for (int j = 0; j < 4; ++j) bv[j] = Bs[kk][tx * 4 + j];
      #pragma unroll
      for (int i = 0; i < 4; ++i)
        #pragma unroll
        for (int j = 0; j < 4; ++j) acc[i][j] += av[i] * bv[j];
    }
    __syncthreads();
  }

  #pragma unroll
  for (int i = 0; i < 4; ++i) {
    int row = m0 + ty * 4 + i;
    float sc = 0.f;
    if constexpr (MODE == 1)
      sc = scale[(long)bz * sScale + row];
    #pragma unroll
    for (int j = 0; j < 4; ++j) {
      int col = n0 + tx * 4 + j;
      float v = acc[i][j];
      if constexpr (MODE == 1) v = sc * v;
      Cb[(long)row * N + col] = v;
    }
  }
}

// ---------------------------------------------------------------------------
// K2 (sparse, f32-exact, deterministic): x1 = relu(dis_i*(sum_{adj_ij!=0} P1_j
// + P1_i) + b1).  One block per row; LDS prefix-scan compaction of nnz.
// ---------------------------------------------------------------------------
__global__ __launch_bounds__(256) void k_spmm_relu(
    const float* __restrict__ adj, const float* __restrict__ P1,
    const float* __restrict__ dis_bin, const float* __restrict__ b1,
    float* __restrict__ x1) {
  long row = blockIdx.x;
  int b = (int)(row >> 10), i = (int)(row & 1023);
  const float* a = adj + row * N_;
  const float* Pb = P1 + (long)b * (long)N_ * H_;
  __shared__ int idxs[N_];
  __shared__ int tcnt[256];
  __shared__ float accs[H_];
  int tid = threadIdx.x;
  int base = tid * 4;
  f32x4 av = *(const f32x4*)(a + base);
  int c0 = (av[0] != 0.0f) + (av[1] != 0.0f) + (av[2] != 0.0f) + (av[3] != 0.0f);
  tcnt[tid] = c0;
  __syncthreads();
  for (int off = 1; off < 256; off <<= 1) {
    int add = (tid >= off) ? tcnt[tid - off] : 0;
    __syncthreads();
    tcnt[tid] += add;
    __syncthreads();
  }
  int pos = tcnt[tid] - c0;
  int n = tcnt[255];
  if (av[0] != 0.0f) idxs[pos++] = base;
  if (av[1] != 0.0f) idxs[pos++] = base + 1;
  if (av[2] != 0.0f) idxs[pos++] = base + 2;
  if (av[3] != 0.0f) idxs[pos++] = base + 3;
  __syncthreads();
  int c = tid & 127, team = tid >> 7;
  float acc = 0.f;
  for (int u = team; u < n; u += 2)
    acc += Pb[(long)idxs[u] * H_ + c];
  if (team == 1) accs[c] = acc;
  __syncthreads();
  if (team == 0) {
    float tot = acc + accs[c] + Pb[(long)i * H_ + c];
    float v = dis_bin[row] * tot + b1[c];
    x1[row * H_ + c] = fmaxf(v, 0.0f);
  }
}

// ---------------------------------------------------------------------------
// Big MFMA GEMM: 128x128 tile, BK=32, global_load_lds staging (m97 structure).
// C = A[M][K] @ Bt[N][K]^T.
// MODE 0: f32 C=acc | 1: bf16 C | 2: f32 floorq | 3: f32 tanh(sc*(acc+Add)+bias)
// ---------------------------------------------------------------------------
template<int MODE>
__global__ __launch_bounds__(256) void mgemm(
    const u16* __restrict__ A, const u16* __restrict__ Bt, void* __restrict__ Cv,
    int M, int N, int K, long sA, long sB, long sC,
    const float* __restrict__ scale, const float* __restrict__ Add, long sAdd,
    const float* __restrict__ bias) {
  int bz = blockIdx.z;
  int m0 = blockIdx.y * 128, n0 = blockIdx.x * 128;
  const u16* Ab = A + (long)bz * sA + (long)m0 * K;
  const u16* Bb = Bt + (long)bz * sB + (long)n0 * K;
  __shared__ __align__(16) u16 As[128 * 32];
  __shared__ __align__(16) u16 Bs[128 * 32];
  int tid = threadIdx.x;
  int lane = tid & 63, wave = tid >> 6;
  int wr = wave >> 1, wc = wave & 1;
  int kg = lane >> 4, r16 = lane & 15;
  const u16* ga = Ab + (long)(tid >> 2) * K + (tid & 3) * 8;
  const u16* gb = Bb + (long)(tid >> 2) * K + (tid & 3) * 8;
  f32x4 acc[4][4] = {};

  for (int k0 = 0; k0 < K; k0 += 32) {
    gload16(ga + k0, &As[tid * 8]);
    gload16(ga + (long)64 * K + k0, &As[2048 + tid * 8]);
    gload16(gb + k0, &Bs[tid * 8]);
    gload16(gb + (long)64 * K + k0, &Bs[2048 + tid * 8]);
    __syncthreads();
    s16x8 af[4], bfr[4];
    #pragma unroll
    for (int m = 0; m < 4; ++m)
      af[m] = *(const s16x8*)(&As[(wr * 64 + m * 16 + r16) * 32 + kg * 8]);
    #pragma unroll
    for (int n = 0; n < 4; ++n)
      bfr[n] = *(const s16x8*)(&Bs[(wc * 64 + n * 16 + r16) * 32 + kg * 8]);
    #pragma unroll
    for (int m = 0; m < 4; ++m)
      #pragma unroll
      for (int n = 0; n < 4; ++n)
        acc[m][n] = __builtin_amdgcn_mfma_f32_16x16x32_bf16(af[m], bfr[n], acc[m][n], 0, 0, 0);
    __syncthreads();
  }

  #pragma unroll
  for (int m = 0; m < 4; ++m) {
    #pragma unroll
    for (int r = 0; r < 4; ++r) {
      int row = m0 + wr * 64 + m * 16 + kg * 4 + r;
      float sc = 0.f;
      if constexpr (MODE == 3) sc = scale[(long)bz * N_ + row];
      #pragma unroll
      for (int n = 0; n < 4; ++n) {
        int col = n0 + wc * 64 + n * 16 + r16;
        float v = acc[m][n][r];
        long cidx = (long)bz * sC + (long)row * N + col;
        if constexpr (MODE == 0) {
          ((float*)Cv)[cidx] = v;
        } else if constexpr (MODE == 1) {
          ((u16*)Cv)[cidx] = f2b(v);
        } else if constexpr (MODE == 2) {
          ((float*)Cv)[cidx] = floorf(v * 10000.0f) / 10000.0f;
        } else {
          v = sc * (v + Add[(long)bz * sAdd + (long)row * N + col]) + bias[col];
          ((float*)Cv)[cidx] = tanhf(v);
        }
      }
    }
  }
}

// ---------------------------------------------------------------------------
// Small-N MFMA GEMM: 64x64 tile, BK=64, reg-staged, pad-72 LDS.
// MODE 0: f32 C=acc | 4: f32 C=scale[row]*acc
// ---------------------------------------------------------------------------
template<int MODE>
__global__ __launch_bounds__(256) void mgemm64(
    const u16* __restrict__ A, const u16* __restrict__ Bt, float* __restrict__ C,
    int M, int N, int K, long sA, long sB, long sC,
    const float* __restrict__ scale, long sScale) {
  int bz = blockIdx.z;
  int m0 = blockIdx.y * 64, n0 = blockIdx.x * 64;
  const u16* Ab = A + (long)bz * sA + (long)m0 * K;
  const u16* Bb = Bt + (long)bz * sB + (long)n0 * K;
  __shared__ __align__(16) u16 As[64 * 72];
  __shared__ __align__(16) u16 Bs[64 * 72];
  int tid = threadIdx.x;
  int lane = tid & 63, wave = tid >> 6;
  int wr = wave >> 1, wc = wave & 1;
  int kg = lane >> 4, r16 = lane & 15;
  f32x4 acc[2][2] = {};

  for (int k0 = 0; k0 < K; k0 += 64) {
    #pragma unroll
    for (int i = 0; i < 2; ++i) {
      int u = tid + i * 256;
      int row = u >> 3, seg = u & 7;
      *(u16x8*)(&As[row * 72 + seg * 8]) = *(const u16x8*)(Ab + (long)row * K + k0 + seg * 8);
      *(u16x8*)(&Bs[row * 72 + seg * 8]) = *(const u16x8*)(Bb + (long)row * K + k0 + seg * 8);
    }
    __syncthreads();
    #pragma unroll
    for (int kk = 0; kk < 2; ++kk) {
      s16x8 af[2], bfr[2];
      #pragma unroll
      for (int m = 0; m < 2; ++m)
        af[m] = *(const s16x8*)(&As[(wr * 32 + m * 16 + r16) * 72 + kk * 32 + kg * 8]);
      #pragma unroll
      for (int n = 0; n < 2; ++n)
        bfr[n] = *(const s16x8*)(&Bs[(wc * 32 + n * 16 + r16) * 72 + kk * 32 + kg * 8]);
      #pragma unroll
      for (int m = 0; m < 2; ++m)
        #pragma unroll
        for (int n = 0; n < 2; ++n)
          acc[m][n] = __builtin_amdgcn_mfma_f32_16x16x32_bf16(af[m], bfr[n], acc[m][n], 0, 0, 0);
    }
    __syncthreads();
  }

  #pragma unroll
  for (int m = 0; m < 2; ++m) {
    #pragma unroll
    for (int r = 0; r < 4; ++r) {
      int row = m0 + wr * 32 + m * 16 + kg * 4 + r;
      float sc = 0.f;
      if constexpr (MODE == 4)
        sc = scale[(long)bz * sScale + row];
      #pragma unroll
      for (int n = 0; n < 2; ++n) {
        int col = n0 + wc * 32 + n * 16 + r16;
        float v = acc[m][n][r];
        if constexpr (MODE == 4) v = sc * v;
        C[(long)bz * sC + (long)row * N + col] = v;
      }
    }
  }
}

// ---------------------------------------------------------------------------
// transpose-convert: X[b][R][C] f32 -> Y[b][C][R] bf16
// ---------------------------------------------------------------------------
__global__ __launch_bounds__(256) void k_convT(
    const float* __restrict__ X, u16* __restrict__ Y, int R, int C,
    long sX, long sY) {
  __shared__ float tile[32][33];
  const float* Xb = X + (long)blockIdx.z * sX;
  u16* Yb = Y + (long)blockIdx.z * sY;
  int tx = threadIdx.x & 31, ty = threadIdx.x >> 5;
  int r0 = blockIdx.y * 32, c0 = blockIdx.x * 32;
  #pragma unroll
  for (int i = 0; i < 4; ++i)
    tile[ty + i * 8][tx] = Xb[(long)(r0 + ty + i * 8) * C + (c0 + tx)];
  __syncthreads();
  #pragma unroll
  for (int i = 0; i < 4; ++i)
    Yb[(long)(c0 + ty + i * 8) * R + (r0 + tx)] = f2b(tile[tx][ty + i * 8]);
}

// flat convert f32 -> bf16
__global__ __launch_bounds__(256) void k_conv(
    const float* __restrict__ X, u16* __restrict__ Y, long n4) {
  long i = (long)blockIdx.x * 256 + threadIdx.x;
  long stride = (long)gridDim.x * 256;
  for (; i < n4; i += stride) {
    f32x4 v = *(const f32x4*)(X + i * 4);
    u16x4 o;
    o[0] = f2b(v[0]); o[1] = f2b(v[1]); o[2] = f2b(v[2]); o[3] = f2b(v[3]);
    *(u16x4*)(Y + i * 4) = o;
  }
}

// binarize: Y[i] = X[i] != 0 ? bf16(1.0) : 0
__global__ __launch_bounds__(256) void k_convbin(
    const float* __restrict__ X, u16* __restrict__ Y, long n) {
  long i = (long)blockIdx.x * 256 + threadIdx.x;
  long stride = (long)gridDim.x * 256;
  for (; i < n; i += stride)
    Y[i] = (X[i] != 0.0f) ? (u16)0x3F80 : (u16)0;
}

// ---------------------------------------------------------------------------
// K4: t[row] = dot(x1[row,:], Watt)
// ---------------------------------------------------------------------------
__global__ __launch_bounds__(256) void k_att_dot(
    const float* __restrict__ x1, const float* __restrict__ Watt,
    float* __restrict__ t) {
  long row = blockIdx.x;
  float v = 0.f;
  if (threadIdx.x < H_) v = x1[row * H_ + threadIdx.x] * Watt[threadIdx.x];
  float s = blockReduceSum256(v);
  if (threadIdx.x == 0) t[row] = s;
}

// ---------------------------------------------------------------------------
// K5: alpha
// ---------------------------------------------------------------------------
__global__ __launch_bounds__(256) void k_alpha(
    const float* __restrict__ adj, const float* __restrict__ dis_bin,
    const float* __restrict__ t, const float* __restrict__ batt,
    float* __restrict__ alpha) {
  long row = blockIdx.x;
  int b = (int)(row >> 10), i = (int)(row & 1023);
  const float* a = adj + row * N_;
  const float* db = dis_bin + (long)b * N_;
  const float* tb = t + (long)b * N_;
  float s = 0.f;
  for (int j = threadIdx.x; j < N_; j += 256)
    if (a[j] != 0.0f) s += db[j] * tb[j];
  s = blockReduceSum256(s);
  if (threadIdx.x == 0) {
    float di = db[i];
    float pre = di * (s + di * tb[i]) + batt[0];
    float z = pre * pre;
    alpha[row] = 1.0f / (1.0f + expf(-z));
  }
}

// ---------------------------------------------------------------------------
// K6: per-batch stable descending sort, cut, index_mask, cut_alpha
// ---------------------------------------------------------------------------
__global__ __launch_bounds__(1024) void k_cutmask(
    const float* __restrict__ alpha, const int* __restrict__ num_sent,
    const int* __restrict__ nout, float* __restrict__ index_mask,
    float* __restrict__ ca) {
  int b = blockIdx.x, tid = threadIdx.x;
  __shared__ unsigned long long keys[N_];
  __shared__ int cs[N_];
  __shared__ int pos_s;
  float av = alpha[(long)b * N_ + tid];
  unsigned int bits = __float_as_uint(av);
  keys[tid] = ((unsigned long long)(0xFFFFFFFFu - bits) << 32) | (unsigned int)tid;
  __syncthreads();
  for (int kk = 2; kk <= N_; kk <<= 1) {
    for (int j = kk >> 1; j > 0; j >>= 1) {
      int ixj = tid ^ j;
      if (ixj > tid) {
        unsigned long long x = keys[tid], y = keys[ixj];
        bool up = ((tid & kk) == 0);
        if ((x > y) == up) { keys[tid] = y; keys[ixj] = x; }
      }
      __syncthreads();
    }
  }
  int ns = num_sent[b];
  int idx = (int)(keys[tid] & 0xFFFFFFFFull);
  cs[tid] = (idx < ns) ? 1 : 0;
  __syncthreads();
  for (int off = 1; off < N_; off <<= 1) {
    int add = (tid >= off) ? cs[tid - off] : 0;
    __syncthreads();
    cs[tid] += add;
    __syncthreads();
  }
  int k = nout[0];
  if (tid == 0) pos_s = 0;
  __syncthreads();
  if (cs[tid] >= k && (tid == 0 || cs[tid - 1] < k)) pos_s = tid;
  __syncthreads();
  float cut = __uint_as_float(0xFFFFFFFFu - (unsigned int)(keys[pos_s] >> 32));
  float myalpha = __uint_as_float(0xFFFFFFFFu - (unsigned int)(keys[tid] >> 32));
  index_mask[(long)b * N_ + idx] = (tid <= pos_s) ? 1.0f : 0.0f;
  ca[(long)b * N_ + idx] = fmaxf((myalpha + 1e-7f) - cut, 0.0f);
}

// ---------------------------------------------------------------------------
// K7: S build + L1 row-normalize
// ---------------------------------------------------------------------------
__global__ __launch_bounds__(256) void k_build_S(
    const float* __restrict__ adj, const float* __restrict__ dr,
    const float* __restrict__ dc, const float* __restrict__ ca,
    float* __restrict__ S) {
  long row = blockIdx.x;
  int b = (int)(row >> 10), i = (int)(row & 1023);
  const float* a = adj + row * N_;
  const float* dcb = dc + (long)b * N_;
  const float* cab = ca + (long)b * N_;
  float dri = dr[row];
  __shared__ float pre[N_];
  float ls = 0.f;
  for (int j = threadIdx.x; j < N_; j += 256) {
    float avv = a[j] + ((j == i) ? 1.0f : 0.0f);
    float v = dri * avv * dcb[j] * cab[j];
    pre[j] = v;
    ls += v;
  }
  float sum = blockReduceSum256(ls);
  float denom = fmaxf(sum, 1e-12f);
  for (int j = threadIdx.x; j < N_; j += 256)
    S[row * N_ + j] = pre[j] / denom;
}

// ---------------------------------------------------------------------------
// K11: dis2 = rsqrt(1 + nnz)
// ---------------------------------------------------------------------------
__global__ __launch_bounds__(256) void k_deg2(
    const float* __restrict__ cadj, float* __restrict__ dis2) {
  long row = blockIdx.x;
  const float* a = cadj + row * N_;
  float cnt = 0.f;
  for (int j = threadIdx.x; j < N_; j += 256)
    if (a[j] != 0.0f) cnt += 1.0f;
  float s = blockReduceSum256(cnt);
  if (threadIdx.x == 0) dis2[row] = rsqrtf(s + 1.0f);
}

// ---------------------------------------------------------------------------
template<int W>
__global__ __launch_bounds__(256) void k_rowmean(
    const float* __restrict__ X, float* __restrict__ out) {
  long row = blockIdx.x;
  float s = 0.f;
  for (int j = threadIdx.x; j < W; j += 256) s += X[row * W + j];
  float r = blockReduceSum256(s);
  if (threadIdx.x == 0) out[row] = r / (float)W;
}

// ---------------------------------------------------------------------------
extern "C" void kernel_launch(void* const* d_in, const int* in_sizes, int n_in,
                              void* d_out, int out_size, void* d_ws, size_t ws_size,
                              hipStream_t stream) {
  const float* x       = (const float*)d_in[0];
  const float* adj     = (const float*)d_in[1];
  const int*   nsent   = (const int*)d_in[2];
  const float* W1      = (const float*)d_in[3];
  const float* b1      = (const float*)d_in[4];
  const float* Watt    = (const float*)d_in[5];
  const float* batt    = (const float*)d_in[6];
  const float* W2      = (const float*)d_in[7];
  const float* b2      = (const float*)d_in[8];
  const int*   nout    = (const int*)d_in[9];

  const long NN = (long)N_ * N_;
  const long NH = (long)N_ * H_;
  const long NF = (long)N_ * F_;
  const int BN = B_ * N_;

  // output layout (flat concat, f32)
  float* out_x2   = (float*)d_out;
  float* out_cx   = out_x2 + (long)B_ * NF;
  float* out_cadj = out_cx + (long)B_ * NH;
  float* out_S    = out_cadj + (long)B_ * NN;
  float* out_im   = out_S + (long)B_ * NN;
  float* out_xs0  = out_im + BN;
  float* out_xs1  = out_xs0 + BN;

  // workspace (~134MB, round-2-proven scale):
  //  P1(8M f32; later cx_bf) | x1(8M) | smalls | W2T | PT(4M: x1T) |
  //  St(32M: St->cbin) | adjT(32M: adjT->P2T) | P2f(50M f32)
  //  StA(32M bf16) lives in out_x2 scratch (written only at the end).
  char* wsb = (char*)d_ws;
  float* P1      = (float*)wsb;
  float* x1      = P1 + (long)B_ * NH;
  float* t       = x1 + (long)B_ * NH;
  float* alpha   = t + BN;
  float* dis_bin = alpha + BN;
  float* dr      = dis_bin + BN;
  float* dc      = dr + BN;
  float* ca      = dc + BN;
  float* dis2    = ca + BN;
  char*  p       = (char*)(dis2 + BN);
  p = (char*)(((size_t)p + 255) & ~(size_t)255);
  u16* W1T   = (u16*)p;  p += (long)H_ * F_ * 2;
  u16* W2T   = (u16*)p;  p += (long)H_ * F_ * 2;
  u16* PT    = (u16*)p;  p += (long)B_ * NH * 2;   // x1T
  u16* St    = (u16*)p;  p += (long)B_ * NN * 2;   // St, then cbin
  u16* adjT  = (u16*)p;  p += (long)B_ * NN * 2;   // adjT, then P2T
  float* P2f = (float*)p;                           // 50MB
  u16* cx_bf = (u16*)P1;
  u16* x1T   = PT;
  u16* cbin  = St;
  u16* P2T   = adjT;
  u16* StA   = (u16*)out_x2;   // scratch in unwritten output region
  (void)W1T;

  // K1: degrees
  k_degrees<<<dim3(BN), dim3(256), 0, stream>>>(adj, dis_bin, dr, dc);

  // G1: P1 = dis_bin .* (x @ W1)  (f32 exact — alpha-critical)
  gemm<0, 0, 1><<<dim3(H_ / TN, BN / TM, 1), dim3(256), 0, stream>>>(
      x, W1, P1, BN, H_, F_, 0, 0, 0, dis_bin, 0, nullptr, 0, nullptr);

  // G2: x1 = relu(dis_i*(Bin(adj)@P1 + P1_i) + b1)  (sparse f32 exact)
  k_spmm_relu<<<dim3(BN), dim3(256), 0, stream>>>(adj, P1, dis_bin, b1, x1);

  // attention + sort + S (f32, unchanged)
  k_att_dot<<<dim3(BN), dim3(256), 0, stream>>>(x1, Watt, t);
  k_alpha<<<dim3(BN), dim3(256), 0, stream>>>(adj, dis_bin, t, batt, alpha);
  k_cutmask<<<dim3(B_), dim3(1024), 0, stream>>>(alpha, nsent, nout, out_im, ca);
  k_build_S<<<dim3(BN), dim3(256), 0, stream>>>(adj, dr, dc, ca, out_S);

  // St = S^T, x1T = x1^T, adjT = adj^T (bf16)
  k_convT<<<dim3(N_ / 32, N_ / 32, B_), dim3(256), 0, stream>>>(out_S, St, N_, N_, NN, NN);
  k_convT<<<dim3(H_ / 32, N_ / 32, B_), dim3(256), 0, stream>>>(x1, x1T, N_, H_, NH, NH);
  k_convT<<<dim3(N_ / 32, N_ / 32, B_), dim3(256), 0, stream>>>(adj, adjT, N_, N_, NN, NN);

  // G5: coarse_x = S^T @ x1  (bf16 MFMA)
  mgemm64<0><<<dim3(H_ / 64, N_ / 64, B_), dim3(256), 0, stream>>>(
      St, x1T, out_cx, N_, H_, N_, NN, NH, NH, nullptr, 0);
  k_rowmean<H_><<<dim3(BN), dim3(256), 0, stream>>>(out_cx, out_xs0);

  // G6: StA = S^T @ adj (bf16 out)
  mgemm<1><<<dim3(N_ / 128, N_ / 128, B_), dim3(256), 0, stream>>>(
      St, adjT, StA, N_, N_, N_, NN, NN, NN, nullptr, nullptr, 0, nullptr);

  // G7: coarse_adj = floorq(StA @ S)
  mgemm<2><<<dim3(N_ / 128, N_ / 128, B_), dim3(256), 0, stream>>>(
      StA, St, out_cadj, N_, N_, N_, NN, NN, NN, nullptr, nullptr, 0, nullptr);

  // K11: dis2
  k_deg2<<<dim3(BN), dim3(256), 0, stream>>>(out_cadj, dis2);

  // cx_bf, W2T
  k_conv<<<dim3(2048), dim3(256), 0, stream>>>(out_cx, cx_bf, (long)B_ * NH / 4);
  k_convT<<<dim3(F_ / 32, H_ / 32, 1), dim3(256), 0, stream>>>(W2, W2T, H_, F_, 0, 0);

  // G8: P2f = dis2 .* (coarse_x @ W2)  (bf16 MFMA)
  mgemm64<4><<<dim3(F_ / 64, BN / 64, 1), dim3(256), 0, stream>>>(
      cx_bf, W2T, P2f, BN, F_, H_, 0, 0, 0, dis2, 0);

  // P2T, cbin
  k_convT<<<dim3(F_ / 32, N_ / 32, B_), dim3(256), 0, stream>>>(P2f, P2T, N_, F_, NF, NF);
  k_convbin<<<dim3(2048), dim3(256), 0, stream>>>(out_cadj, cbin, (long)B_ * NN);

  // G9: x2 = tanh(dis2_i*(cbin@P2 + P2_i) + b2)   (overwrites StA scratch)
  mgemm<3><<<dim3(F_ / 128, N_ / 128, B_), dim3(256), 0, stream>>>(
      cbin, P2T, out_x2, N_, F_, N_, NN, NF, NF, dis2, P2f, NF, b2);

  k_rowmean<F_><<<dim3(BN), dim3(256), 0, stream>>>(out_x2, out_xs1);
}